// Round 14
// baseline (221.540 us; speedup 1.0000x reference)
//
#include <hip/hip_runtime.h>
#include <cstdint>
#include <cstddef>

// Problem constants (match reference)
#define BB    64
#define TB    2000
#define KB    256
#define NSCB  32       // scan blocks: 2 batches per block, interleaved in wave 0
#define WPB   125      // lse wave-jobs per batch
#define RPW   16       // rows per lse wave-job (125*16 = 2000)
#define NLSEB 2000     // lse blocks (4 waves each): 64*125/4

constexpr float LOG2E = 1.4426950408889634f;
constexpr float LN2f  = 0.6931471805599453f;
constexpr float WBF   = 0.36787944117144233f;   // exp(-1)

__device__ __forceinline__ float exp2i(int k) {  // exact 2^k, k in [-126,127]
  return __uint_as_float((uint32_t)(127 + k) << 23);
}
// lane i <- lane i-1 (lane 0 <- 0): DPP wave_shr:1 (validated r4-r11)
__device__ __forceinline__ float shr1z(float v) {
  return __int_as_float(__builtin_amdgcn_update_dpp(
      0, __float_as_int(v), 0x138, 0xF, 0xF, true));
}
// wave64 max, pure-VALU DPP tree (validated r6-r11); uniform via readlane(63)
__device__ __forceinline__ float dmax64(float v) {
#define DSTEP(ctrl, rm, bc)                                                  \
  { float t = __int_as_float(__builtin_amdgcn_update_dpp(                    \
        __float_as_int(v), __float_as_int(v), (ctrl), (rm), 0xF, (bc)));     \
    v = fmaxf(v, t); }
  DSTEP(0x111, 0xF, true) DSTEP(0x112, 0xF, true) DSTEP(0x114, 0xF, true)
  DSTEP(0x118, 0xF, true) DSTEP(0x142, 0xA, false) DSTEP(0x143, 0xC, false)
#undef DSTEP
  return __int_as_float(__builtin_amdgcn_readlane(__float_as_int(v), 63));
}
// wave64 sum, pure-VALU DPP tree; total valid in lane 63 (validated r6-r11)
__device__ __forceinline__ float dsum64(float v) {
#define DSTEP(ctrl, rm, bc)                                                  \
  { float t = __int_as_float(__builtin_amdgcn_update_dpp(                    \
        __float_as_int(v), __float_as_int(v), (ctrl), (rm), 0xF, (bc)));     \
    v += t; }
  DSTEP(0x111, 0xF, true) DSTEP(0x112, 0xF, true) DSTEP(0x114, 0xF, true)
  DSTEP(0x118, 0xF, true) DSTEP(0x142, 0xA, false) DSTEP(0x143, 0xC, false)
#undef DSTEP
  return v;
}
__device__ __forceinline__ float wsum64(float v) {
#pragma unroll
  for (int m = 32; m >= 1; m >>= 1) v += __shfl_xor(v, m, 64);
  return v;
}

// ---------------------------------------------------------------------------
// blocks [0,32): TWO batches per block, interleaved in ONE consumer wave.
//   wave 0: consumer — batches 2i and 2i+1 step-interleaved (ILP fills the
//           dependent-latency slots that made r11's single chain 145 cyc/step)
//   waves 1-3: producers (r11 structure): per own group, stage 8 weight rows
//           of batch A into ringA and 8 of batch B into ringB.
// blocks >= 32: row lse, 16 rows/wave, loads fully hoisted (16 in flight).
// All per-batch arithmetic is bit-identical to r11 (passing, absmax 0.5).
// ---------------------------------------------------------------------------
__global__ __launch_bounds__(256, 1)
void fsl_main(const float* __restrict__ x, const int* __restrict__ key_lens,
              const int* __restrict__ query_lens, float* __restrict__ partial,
              float* __restrict__ alast, float* __restrict__ aprev) {
  __shared__ __align__(16) char ring2[131072];  // ringA @0, ringB @65536
  __shared__ __align__(16) int prodG[4];        // 3 flags + 0x7fffffff pad
  __shared__ int consG;

  const int tid  = threadIdx.x;
  const int lane = tid & 63;
  const int w    = tid >> 6;

  if (blockIdx.x < NSCB) {
    const int bA = blockIdx.x * 2;
    const int bB = bA + 1;
    const int klA = key_lens[bA], klB = key_lens[bB];
    const int qA = query_lens[bA], qB = query_lens[bB];
    const int totA = qA - 1, totB = qB - 1;
    const int ngA = (totA + 7) >> 3, ngB = (totB + 7) >> 3;
    const int NG = max(ngA, ngB);              // >= 125
    const char* xbcA = (const char*)(x + (size_t)bA * (TB * KB));
    const char* xbcB = (const char*)(x + (size_t)bB * (TB * KB));
    const int lane16 = lane << 4;
    char* const ringA = ring2;
    char* const ringB = ring2 + 65536;

    if (tid == 0) { prodG[0] = 0; prodG[1] = 0; prodG[2] = 0;
                    prodG[3] = 0x7fffffff; consG = 0; }
    __syncthreads();                           // the ONLY barrier

#define POLL(GN) do {                                                        \
    const int tgt_ = (GN);                                                   \
    for (;;) {                                                               \
      __asm__ __volatile__("" ::: "memory");                                 \
      const int4 fl_ = *(const int4*)prodG;                                  \
      if (min(fl_.x, min(fl_.y, fl_.z)) >= tgt_) break;                      \
    }                                                                        \
    __asm__ __volatile__("" ::: "memory");                                   \
  } while (0)

#define LD8(E, g, RING) do {                                                 \
    const char* sb_ = (RING) + (((g) & 7) << 13) + lane16;                   \
    E##0 = *(const float4*)(sb_);                                            \
    E##1 = *(const float4*)(sb_ + 1024);                                     \
    E##2 = *(const float4*)(sb_ + 2048);                                     \
    E##3 = *(const float4*)(sb_ + 3072);                                     \
    E##4 = *(const float4*)(sb_ + 4096);                                     \
    E##5 = *(const float4*)(sb_ + 5120);                                     \
    E##6 = *(const float4*)(sb_ + 6144);                                     \
    E##7 = *(const float4*)(sb_ + 7168);                                     \
  } while (0)

    if (w == 0) {
      // ============== consumer: both batches in one wave ==============
      float aA0 = 0.f, aA1 = 0.f, aA2 = 0.f, aA3 = 0.f;
      float bA0 = 0.f, bA1 = 0.f, bA2 = 0.f, bA3 = 0.f, sA512 = 0.f;
      float aB0 = 0.f, aB1 = 0.f, aB2 = 0.f, aB3 = 0.f;
      float bB0 = 0.f, bB1 = 0.f, bB2 = 0.f, bB3 = 0.f, sB512 = 0.f;
      if (lane == 0) {
        aA0 = WBF; bA0 = __builtin_amdgcn_exp2f(((const float*)xbcA)[0] * LOG2E);
        aB0 = WBF; bB0 = __builtin_amdgcn_exp2f(((const float*)xbcB)[0] * LOG2E);
      }
      int CwA = 0, CwB = 0;
      float mrA = dmax64(fmaxf(aA0, bA0));
      float mrB = dmax64(fmaxf(aB0, bB0));

      float4 eA0, eA1, eA2, eA3, eA4, eA5, eA6, eA7;
      float4 fA0, fA1, fA2, fA3, fA4, fA5, fA6, fA7;
      float4 eB0, eB1, eB2, eB3, eB4, eB5, eB6, eB7;
      float4 fB0, fB1, fB2, fB3, fB4, fB5, fB6, fB7;

      // per-batch step (bit-identical to r11's STEP1)
#define STEP1N(EV, a0,a1,a2,a3, b0,b1,b2,b3, s512) do {                      \
    const float pm1 = shr1z(b3);                                             \
    const float t0_ = a0 + pm1;                                              \
    const float t1_ = a1 + b0;                                               \
    const float t2_ = a2 + b1;                                               \
    const float t3_ = a3 + b2;                                               \
    s512 = s512 + b3;                                                        \
    b0 = (b0 + t0_) * EV.x;                                                  \
    b1 = (b1 + t1_) * EV.y;                                                  \
    b2 = (b2 + t2_) * EV.z;                                                  \
    b3 = (b3 + t3_) * EV.w;                                                  \
    a0 = t0_; a1 = t1_; a2 = t2_; a3 = t3_;                                  \
  } while (0)
#define STEPA(EV) STEP1N(EV, aA0,aA1,aA2,aA3, bA0,bA1,bA2,bA3, sA512)
#define STEPB(EV) STEP1N(EV, aB0,aB1,aB2,aB3, bB0,bB1,bB2,bB3, sB512)

      // interleaved step-pair: A and B chains fill each other's latency
#define STEPP(EA, EB) do { STEPA(EA); STEPB(EB); } while (0)
#define RUN8P(PA, PB) do {                                                   \
    STEPP(PA##0, PB##0); STEPP(PA##1, PB##1);                                \
    STEPP(PA##2, PB##2); STEPP(PA##3, PB##3);                                \
    STEPP(PA##4, PB##4); STEPP(PA##5, PB##5);                                \
    STEPP(PA##6, PB##6); STEPP(PA##7, PB##7);                                \
  } while (0)

#define RUN8A(E) do { STEPA(E##0); STEPA(E##1); STEPA(E##2); STEPA(E##3);    \
                      STEPA(E##4); STEPA(E##5); STEPA(E##6); STEPA(E##7); } while (0)
#define RUN8B(E) do { STEPB(E##0); STEPB(E##1); STEPB(E##2); STEPB(E##3);    \
                      STEPB(E##4); STEPB(E##5); STEPB(E##6); STEPB(E##7); } while (0)
#define RUN8GA(E, RM) do { const int rem_ = (RM);                            \
    if (0 < rem_) STEPA(E##0); if (1 < rem_) STEPA(E##1);                    \
    if (2 < rem_) STEPA(E##2); if (3 < rem_) STEPA(E##3);                    \
    if (4 < rem_) STEPA(E##4); if (5 < rem_) STEPA(E##5);                    \
    if (6 < rem_) STEPA(E##6); if (7 < rem_) STEPA(E##7); } while (0)
#define RUN8GB(E, RM) do { const int rem_ = (RM);                            \
    if (0 < rem_) STEPB(E##0); if (1 < rem_) STEPB(E##1);                    \
    if (2 < rem_) STEPB(E##2); if (3 < rem_) STEPB(E##3);                    \
    if (4 < rem_) STEPB(E##4); if (5 < rem_) STEPB(E##5);                    \
    if (6 < rem_) STEPB(E##6); if (7 < rem_) STEPB(E##7); } while (0)

#define APPLYN(mr, Cw, a0,a1,a2,a3, b0,b1,b2,b3, s512) do {                  \
    int e_ = (int)((__float_as_uint(mr) >> 23) & 0xFF) - 127;                \
    if (!((mr) > 0.f)) e_ = -24;                                             \
    const int k_ = e_ + 24;              /* normalize max to 2^-24 */        \
    if (k_ > 126) {                                                          \
      const int kh_ = k_ >> 1;                                               \
      const float s1_ = exp2i(-kh_), s2_ = exp2i(-(k_ - kh_));               \
      a0 *= s1_; a1 *= s1_; a2 *= s1_; a3 *= s1_;                            \
      b0 *= s1_; b1 *= s1_; b2 *= s1_; b3 *= s1_; s512 *= s1_;               \
      a0 *= s2_; a1 *= s2_; a2 *= s2_; a3 *= s2_;                            \
      b0 *= s2_; b1 *= s2_; b2 *= s2_; b3 *= s2_; s512 *= s2_;               \
    } else {                                                                 \
      const float s_ = exp2i(-k_);                                           \
      a0 *= s_; a1 *= s_; a2 *= s_; a3 *= s_;                                \
      b0 *= s_; b1 *= s_; b2 *= s_; b3 *= s_; s512 *= s_;                    \
    }                                                                        \
    Cw += k_;                                                                \
  } while (0)
#define MEASN(mr, a0,a1,a2,a3, b0,b1,b2,b3, s512) do {                       \
    float ml_ = fmaxf(fmaxf(fmaxf(a0, a1), fmaxf(a2, a3)),                   \
                      fmaxf(fmaxf(b0, b1), fmaxf(b2, b3)));                  \
    ml_ = fmaxf(ml_, s512);                                                  \
    mr = dmax64(ml_);                                                        \
  } while (0)
#define APPLYA() APPLYN(mrA, CwA, aA0,aA1,aA2,aA3, bA0,bA1,bA2,bA3, sA512)
#define APPLYB() APPLYN(mrB, CwB, aB0,aB1,aB2,aB3, bB0,bB1,bB2,bB3, sB512)
#define MEASA()  MEASN(mrA, aA0,aA1,aA2,aA3, bA0,bA1,bA2,bA3, sA512)
#define MEASB()  MEASN(mrB, aB0,aB1,aB2,aB3, bB0,bB1,bB2,bB3, sB512)

      // one group for both batches (full-interleave fast path; guarded else)
#define GRP(PA, PB, G) do {                                                  \
    const bool fA_ = (8 * (G) + 8 <= totA), fB_ = (8 * (G) + 8 <= totB);     \
    if (fA_ && fB_) { RUN8P(PA, PB); }                                       \
    else {                                                                   \
      if (fA_) { RUN8A(PA); }                                                \
      else if (8 * (G) < totA) { RUN8GA(PA, totA - 8 * (G)); }               \
      if (fB_) { RUN8B(PB); }                                                \
      else if (8 * (G) < totB) { RUN8GB(PB, totB - 8 * (G)); }               \
    }                                                                        \
    APPLYA(); MEASA(); APPLYB(); MEASB();                                    \
  } while (0)

      POLL(3);
      LD8(eA, 0, ringA); LD8(eB, 0, ringB);
      LD8(fA, 1, ringA); LD8(fB, 1, ringB);    // NG >= 125: always valid
      int g = 0;
      for (;;) {
        POLL(min(g + 3, NG));
        GRP(eA, eB, g);
        if (g + 2 < NG) { LD8(eA, g + 2, ringA); LD8(eB, g + 2, ringB); }
        __asm__ __volatile__("" ::: "memory");
        if (lane == 0) *(volatile int*)&consG = g + 3;
        if (++g >= NG) break;
        POLL(min(g + 3, NG));
        GRP(fA, fB, g);
        if (g + 2 < NG) { LD8(fA, g + 2, ringA); LD8(fB, g + 2, ringB); }
        __asm__ __volatile__("" ::: "memory");
        if (lane == 0) *(volatile int*)&consG = g + 3;
        if (++g >= NG) break;
      }
#undef STEP1N
#undef STEPA
#undef STEPB
#undef STEPP
#undef RUN8P
#undef RUN8A
#undef RUN8B
#undef RUN8GA
#undef RUN8GB
#undef APPLYN
#undef MEASN
#undef APPLYA
#undef APPLYB
#undef MEASA
#undef MEASB
#undef GRP

      // readout per batch (r11 layout: ev = a's, od = b's, s512 at +8192)
      *(float4*)((float*)ringA + (lane << 2)) = make_float4(aA0, aA1, aA2, aA3);
      *(float4*)((float*)(ringA + 4096) + (lane << 2)) = make_float4(bA0, bA1, bA2, bA3);
      if (lane == 63) *(float*)(ringA + 8192) = sA512;
      *(float4*)((float*)ringB + (lane << 2)) = make_float4(aB0, aB1, aB2, aB3);
      *(float4*)((float*)(ringB + 4096) + (lane << 2)) = make_float4(bB0, bB1, bB2, bB3);
      if (lane == 63) *(float*)(ringB + 8192) = sB512;
      __asm__ __volatile__("" ::: "memory");
      if (lane == 0) {
        const float aLA = (klA < 256) ? ((const float*)ringA)[klA]
                                      : *(const float*)(ringA + 8192);
        const float aPA = ((const float*)(ringA + 4096))[klA - 1];
        const float dCA = (float)CwA - (float)totA * LOG2E;
        alast[bA] = (log2f(aLA) + dCA) * LN2f;
        aprev[bA] = (log2f(aPA) + dCA) * LN2f;
        const float aLB = (klB < 256) ? ((const float*)ringB)[klB]
                                      : *(const float*)(ringB + 8192);
        const float aPB = ((const float*)(ringB + 4096))[klB - 1];
        const float dCB = (float)CwB - (float)totB * LOG2E;
        alast[bB] = (log2f(aLB) + dCB) * LN2f;
        aprev[bB] = (log2f(aPB) + dCB) * LN2f;
      }
    } else {
      // ========== producers: waves 1..3 — stage BOTH rings ==========
      const int pw = w - 1;                    // own groups: g % 3 == pw
      const int c0 = lane << 2;
      const float bsA0 = (c0 + 0 < klA) ? LOG2E : -20000.f;
      const float bsA1 = (c0 + 1 < klA) ? LOG2E : -20000.f;
      const float bsA2 = (c0 + 2 < klA) ? LOG2E : -20000.f;
      const float bsA3 = (c0 + 3 < klA) ? LOG2E : -20000.f;
      const float bsB0 = (c0 + 0 < klB) ? LOG2E : -20000.f;
      const float bsB1 = (c0 + 1 < klB) ? LOG2E : -20000.f;
      const float bsB2 = (c0 + 2 < klB) ? LOG2E : -20000.f;
      const float bsB3 = (c0 + 3 < klB) ? LOG2E : -20000.f;
      volatile int* vc = &consG;

      float4 XA0, XA1, XA2, XA3, XA4, XA5, XA6, XA7;
      float4 XB0, XB1, XB2, XB3, XB4, XB5, XB6, XB7;
      float4 YA0, YA1, YA2, YA3, YA4, YA5, YA6, YA7;
      float4 YB0, YB1, YB2, YB3, YB4, YB5, YB6, YB7;

#define LOADG2(PA, PB, GG) do {                                              \
    const int rb_ = 8 * (GG) + 1;                                            \
    PA##0 = *(const float4*)(xbcA + (size_t)min(rb_ + 0, TB - 1) * 1024 + lane16); \
    PA##1 = *(const float4*)(xbcA + (size_t)min(rb_ + 1, TB - 1) * 1024 + lane16); \
    PA##2 = *(const float4*)(xbcA + (size_t)min(rb_ + 2, TB - 1) * 1024 + lane16); \
    PA##3 = *(const float4*)(xbcA + (size_t)min(rb_ + 3, TB - 1) * 1024 + lane16); \
    PA##4 = *(const float4*)(xbcA + (size_t)min(rb_ + 4, TB - 1) * 1024 + lane16); \
    PA##5 = *(const float4*)(xbcA + (size_t)min(rb_ + 5, TB - 1) * 1024 + lane16); \
    PA##6 = *(const float4*)(xbcA + (size_t)min(rb_ + 6, TB - 1) * 1024 + lane16); \
    PA##7 = *(const float4*)(xbcA + (size_t)min(rb_ + 7, TB - 1) * 1024 + lane16); \
    PB##0 = *(const float4*)(xbcB + (size_t)min(rb_ + 0, TB - 1) * 1024 + lane16); \
    PB##1 = *(const float4*)(xbcB + (size_t)min(rb_ + 1, TB - 1) * 1024 + lane16); \
    PB##2 = *(const float4*)(xbcB + (size_t)min(rb_ + 2, TB - 1) * 1024 + lane16); \
    PB##3 = *(const float4*)(xbcB + (size_t)min(rb_ + 3, TB - 1) * 1024 + lane16); \
    PB##4 = *(const float4*)(xbcB + (size_t)min(rb_ + 4, TB - 1) * 1024 + lane16); \
    PB##5 = *(const float4*)(xbcB + (size_t)min(rb_ + 5, TB - 1) * 1024 + lane16); \
    PB##6 = *(const float4*)(xbcB + (size_t)min(rb_ + 6, TB - 1) * 1024 + lane16); \
    PB##7 = *(const float4*)(xbcB + (size_t)min(rb_ + 7, TB - 1) * 1024 + lane16); \
  } while (0)

#define PR1M(V, J, M0, M1, M2, M3, DST) do {                                 \
    float4 wv_;                                                              \
    wv_.x = __builtin_amdgcn_exp2f(fmaf(V.x, LOG2E, M0));                    \
    wv_.y = __builtin_amdgcn_exp2f(fmaf(V.y, LOG2E, M1));                    \
    wv_.z = __builtin_amdgcn_exp2f(fmaf(V.z, LOG2E, M2));                    \
    wv_.w = __builtin_amdgcn_exp2f(fmaf(V.w, LOG2E, M3));                    \
    *(float4*)((DST) + ((J) << 10)) = wv_;                                   \
  } while (0)

#define PROC2(PA, PB, GG) do {                                               \
    if ((GG) >= 8) {                        /* ring slot reuse */            \
      int c_ = *vc;                                                          \
      while (c_ < (GG) - 7) { __builtin_amdgcn_s_sleep(2); c_ = *vc; }       \
      __asm__ __volatile__("" ::: "memory");                                 \
    }                                                                        \
    char* dA_ = ringA + (((GG) & 7) << 13) + lane16;                         \
    char* dB_ = ringB + (((GG) & 7) << 13) + lane16;                         \
    PR1M(PA##0, 0, bsA0, bsA1, bsA2, bsA3, dA_);                             \
    PR1M(PA##1, 1, bsA0, bsA1, bsA2, bsA3, dA_);                             \
    PR1M(PA##2, 2, bsA0, bsA1, bsA2, bsA3, dA_);                             \
    PR1M(PA##3, 3, bsA0, bsA1, bsA2, bsA3, dA_);                             \
    PR1M(PA##4, 4, bsA0, bsA1, bsA2, bsA3, dA_);                             \
    PR1M(PA##5, 5, bsA0, bsA1, bsA2, bsA3, dA_);                             \
    PR1M(PA##6, 6, bsA0, bsA1, bsA2, bsA3, dA_);                             \
    PR1M(PA##7, 7, bsA0, bsA1, bsA2, bsA3, dA_);                             \
    PR1M(PB##0, 0, bsB0, bsB1, bsB2, bsB3, dB_);                             \
    PR1M(PB##1, 1, bsB0, bsB1, bsB2, bsB3, dB_);                             \
    PR1M(PB##2, 2, bsB0, bsB1, bsB2, bsB3, dB_);                             \
    PR1M(PB##3, 3, bsB0, bsB1, bsB2, bsB3, dB_);                             \
    PR1M(PB##4, 4, bsB0, bsB1, bsB2, bsB3, dB_);                             \
    PR1M(PB##5, 5, bsB0, bsB1, bsB2, bsB3, dB_);                             \
    PR1M(PB##6, 6, bsB0, bsB1, bsB2, bsB3, dB_);                             \
    PR1M(PB##7, 7, bsB0, bsB1, bsB2, bsB3, dB_);                             \
    __asm__ __volatile__("s_waitcnt lgkmcnt(0)" ::: "memory");               \
    if (lane == 0) *(volatile int*)&prodG[pw] = (GG) + 3;                    \
  } while (0)

      LOADG2(XA, XB, pw);
      LOADG2(YA, YB, pw + 3);
      int g = pw;
      for (;;) {
        PROC2(XA, XB, g);
        g += 3; if (g >= NG) break;
        if (g + 3 < NG) LOADG2(XA, XB, g + 3);
        PROC2(YA, YB, g);
        g += 3; if (g >= NG) break;
        if (g + 3 < NG) LOADG2(YA, YB, g + 3);
      }
#undef LOADG2
#undef PR1M
#undef PROC2
      __asm__ __volatile__("" ::: "memory");
      if (lane == 0) *(volatile int*)&prodG[pw] = 0x7fffffff;
    }
#undef POLL
#undef LD8

  } else {
    // ------ lse row partials: 16 rows/wave, all 16 loads in flight ------
    const int gwid = (blockIdx.x - NSCB) * 4 + w;          // [0, 8000)
    const int b    = gwid / WPB;
    const int widx = gwid - b * WPB;
    const int kl   = key_lens[b];
    const int qlen = query_lens[b];
    const float* xb = x + (size_t)b * (TB * KB);
    const int c0 = lane * 4;
    const float bA = (c0 + 0 < kl) ? 0.f : -20000.f;
    const float bBv= (c0 + 1 < kl) ? 0.f : -20000.f;
    const float bC = (c0 + 2 < kl) ? 0.f : -20000.f;
    const float bD = (c0 + 3 < kl) ? 0.f : -20000.f;
    const int tbase = widx * RPW;
#define LSELOAD(k) const float4 v##k =                                       \
    *(const float4*)(xb + (size_t)(tbase + (k)) * KB + c0);
    LSELOAD(0)  LSELOAD(1)  LSELOAD(2)  LSELOAD(3)
    LSELOAD(4)  LSELOAD(5)  LSELOAD(6)  LSELOAD(7)
    LSELOAD(8)  LSELOAD(9)  LSELOAD(10) LSELOAD(11)
    LSELOAD(12) LSELOAD(13) LSELOAD(14) LSELOAD(15)
#undef LSELOAD
    float acc = 0.f;
#define LSEROW(k) do {                                                       \
    float s = __builtin_amdgcn_exp2f(fmaf(v##k.x, LOG2E, bA))                \
            + __builtin_amdgcn_exp2f(fmaf(v##k.y, LOG2E, bBv))               \
            + __builtin_amdgcn_exp2f(fmaf(v##k.z, LOG2E, bC))                \
            + __builtin_amdgcn_exp2f(fmaf(v##k.w, LOG2E, bD));               \
    s = dsum64(s);                                                           \
    s += WBF;                                                                \
    acc += ((tbase + (k)) < qlen) ? __builtin_amdgcn_logf(s) : 0.f;          \
  } while (0)
    LSEROW(0);  LSEROW(1);  LSEROW(2);  LSEROW(3);
    LSEROW(4);  LSEROW(5);  LSEROW(6);  LSEROW(7);
    LSEROW(8);  LSEROW(9);  LSEROW(10); LSEROW(11);
    LSEROW(12); LSEROW(13); LSEROW(14); LSEROW(15);
#undef LSEROW
    if (lane == 63) partial[gwid] = acc * LN2f;
  }
}

// ---------------------------------------------------------------------------
// finish: per-batch SumLse + loss + mean, one block (r5-proven).
// ---------------------------------------------------------------------------
__global__ __launch_bounds__(256)
void fsl_finish(const float* __restrict__ partial, const int* __restrict__ key_lens,
                const float* __restrict__ alast, const float* __restrict__ aprev,
                float* __restrict__ out) {
  const int tid = threadIdx.x;
  const int b = tid >> 2, q = tid & 3;
  float s = 0.f;
  for (int j = q; j < WPB; j += 4) s += partial[b * WPB + j];
  s += __shfl_xor(s, 1, 64);
  s += __shfl_xor(s, 2, 64);
  float lossb = 0.f;
  if (q == 0) {
    const float SumLse = s;
    const float al = alast[b], ap = aprev[b];
    const float mx = fmaxf(al, ap);
    const float lae = (mx == -INFINITY) ? -INFINITY
                                        : mx + log1pf(expf(-fabsf(al - ap)));
    const float nll = SumLse - lae;
    const int kl = key_lens[b];
    float lv = nll / (float)max(kl, 1);
    if (nll > 5e29f) lv = 0.f;
    lossb = lv;
  }
  float v = wsum64(lossb);
  __shared__ float sm[4];
  if ((tid & 63) == 0) sm[tid >> 6] = v;
  __syncthreads();
  if (tid == 0) out[0] = ((sm[0] + sm[1]) + (sm[2] + sm[3])) * (1.0f / 64.0f);
}

extern "C" void kernel_launch(void* const* d_in, const int* in_sizes, int n_in,
                              void* d_out, int out_size, void* d_ws, size_t ws_size,
                              hipStream_t stream) {
  const float* x     = (const float*)d_in[0];
  const int*   klens = (const int*)d_in[1];
  const int*   qlens = (const int*)d_in[2];
  float* out = (float*)d_out;

  float* partial = (float*)d_ws;            // 64*125 = 8000 floats
  float* alast   = partial + BB * WPB;      // 64
  float* aprev   = alast + BB;              // 64

  fsl_main  <<<NSCB + NLSEB, 256, 0, stream>>>(x, klens, qlens, partial, alast, aprev);
  fsl_finish<<<1, 256, 0, stream>>>(partial, klens, alast, aprev, out);
}

// Round 16
// 121.672 us; speedup vs baseline: 1.8208x; 1.8208x over previous
//
#include <hip/hip_runtime.h>
#include <cstdint>
#include <cstddef>

// Problem constants (match reference)
#define BB    64
#define TB    2000
#define KB    256
#define WPB   125      // lse wave-jobs per batch
#define RPW   16       // rows per lse wave-job (125*16 = 2000)
#define NLSEB 2000     // lse blocks (4 waves each): 64*125/4

constexpr float LOG2E = 1.4426950408889634f;
constexpr float LN2f  = 0.6931471805599453f;
constexpr float WBF   = 0.36787944117144233f;   // exp(-1)

__device__ __forceinline__ float exp2i(int k) {  // exact 2^k, k in [-126,127]
  return __uint_as_float((uint32_t)(127 + k) << 23);
}
// lane i <- lane i-1 (lane 0 <- 0): DPP wave_shr:1 (validated r4-r11)
__device__ __forceinline__ float shr1z(float v) {
  return __int_as_float(__builtin_amdgcn_update_dpp(
      0, __float_as_int(v), 0x138, 0xF, 0xF, true));
}
// wave64 max, pure-VALU DPP tree (validated r6-r11); uniform via readlane(63)
__device__ __forceinline__ float dmax64(float v) {
#define DSTEP(ctrl, rm, bc)                                                  \
  { float t = __int_as_float(__builtin_amdgcn_update_dpp(                    \
        __float_as_int(v), __float_as_int(v), (ctrl), (rm), 0xF, (bc)));     \
    v = fmaxf(v, t); }
  DSTEP(0x111, 0xF, true) DSTEP(0x112, 0xF, true) DSTEP(0x114, 0xF, true)
  DSTEP(0x118, 0xF, true) DSTEP(0x142, 0xA, false) DSTEP(0x143, 0xC, false)
#undef DSTEP
  return __int_as_float(__builtin_amdgcn_readlane(__float_as_int(v), 63));
}
// wave64 sum, pure-VALU DPP tree; total valid in lane 63 (validated r6-r11)
__device__ __forceinline__ float dsum64(float v) {
#define DSTEP(ctrl, rm, bc)                                                  \
  { float t = __int_as_float(__builtin_amdgcn_update_dpp(                    \
        __float_as_int(v), __float_as_int(v), (ctrl), (rm), 0xF, (bc)));     \
    v += t; }
  DSTEP(0x111, 0xF, true) DSTEP(0x112, 0xF, true) DSTEP(0x114, 0xF, true)
  DSTEP(0x118, 0xF, true) DSTEP(0x142, 0xA, false) DSTEP(0x143, 0xC, false)
#undef DSTEP
  return v;
}
__device__ __forceinline__ float wsum64(float v) {
#pragma unroll
  for (int m = 32; m >= 1; m >>= 1) v += __shfl_xor(v, m, 64);
  return v;
}

// ---------------------------------------------------------------------------
// r16 = r11 + register PINS (scalar-component form; r15's float4 "v" operand
// is not supported by hipcc inline asm).
// blocks [0,64): per-batch scan. Wave 0 = consumer (513 states, 4 pairs/lane,
// 1 DPP shift/step, zero transcendentals, zero barriers). Waves 1-3 =
// producers: load x rows, 4 exp2/row (bias bakes key-mask + e^1-fold),
// ds_write weight rows into an 8-group LDS ring.
// PIN8(E): asm reads every component of the group buffer right before RUN8 —
// anchors the 8 ds_read_b128s before the group (one bulk lgkm wait) instead
// of letting the scheduler sink them to per-step positions (the suspected
// ~120cyc/step constant of r8-r14).
// blocks >= 64: row lse, 16 rows/wave, DPP sum (r5/r6-proven).
// ---------------------------------------------------------------------------
__global__ __launch_bounds__(256, 1)
void fsl_main(const float* __restrict__ x, const int* __restrict__ key_lens,
              const int* __restrict__ query_lens, float* __restrict__ partial,
              float* __restrict__ alast, float* __restrict__ aprev) {
  __shared__ __align__(16) char ring[86016];   // 64KB ring (8 x 8KB) + pad
  __shared__ __align__(16) int prodG[4];       // 3 flags + pad (one b128 read)
  __shared__ int consG;

  const int tid  = threadIdx.x;
  const int lane = tid & 63;
  const int w    = tid >> 6;

  if (blockIdx.x < BB) {
    const int b    = blockIdx.x;
    const int kl   = key_lens[b];
    const int qlen = query_lens[b];
    const int total = qlen - 1;                // live steps t = 1..total
    const int ng    = (total + 7) >> 3;        // 8-step groups (>=125)
    const float* xb  = x + (size_t)b * (TB * KB);
    const char*  xbc = (const char*)xb;
    const int lane16 = lane << 4;

    if (tid == 0) { prodG[0] = 0; prodG[1] = 0; prodG[2] = 0; prodG[3] = 0x7fffffff; consG = 0; }
    __syncthreads();                           // the ONLY barrier

    if (w == 0) {
      // =================== consumer: the scan wave ===================
      float a0 = 0.f, a1 = 0.f, a2 = 0.f, a3 = 0.f;
      float b0 = 0.f, b1 = 0.f, b2 = 0.f, b3 = 0.f, s512 = 0.f;
      if (lane == 0) { a0 = WBF; b0 = __builtin_amdgcn_exp2f(xb[0] * LOG2E); }
      int Cw = 0;
      float m_red = dmax64(fmaxf(a0, b0));

      float4 e0, e1, e2, e3, e4, e5, e6, e7;
      float4 f0, f1, f2, f3, f4, f5, f6, f7;
      float4 g0, g1, g2, g3, g4, g5, g6, g7;

      // one ds_read_b128 of all 3 flags; pure spin (scan CU is exclusive)
#define POLL(GN) do {                                                        \
    const int tgt_ = (GN);                                                   \
    for (;;) {                                                               \
      __asm__ __volatile__("" ::: "memory");                                 \
      const int4 fl_ = *(const int4*)prodG;                                  \
      if (min(fl_.x, min(fl_.y, fl_.z)) >= tgt_) break;                      \
    }                                                                        \
    __asm__ __volatile__("" ::: "memory");                                   \
  } while (0)

#define LD8(E, g) do {                                                       \
    const char* sb_ = ring + (((g) & 7) << 13) + lane16;                     \
    E##0 = *(const float4*)(sb_);                                            \
    E##1 = *(const float4*)(sb_ + 1024);                                     \
    E##2 = *(const float4*)(sb_ + 2048);                                     \
    E##3 = *(const float4*)(sb_ + 3072);                                     \
    E##4 = *(const float4*)(sb_ + 4096);                                     \
    E##5 = *(const float4*)(sb_ + 5120);                                     \
    E##6 = *(const float4*)(sb_ + 6144);                                     \
    E##7 = *(const float4*)(sb_ + 7168);                                     \
  } while (0)

      // PIN: scalar-component asm reads -> loads cannot sink past here.
#define PINV(V) __asm__ __volatile__("" ::                                   \
    "v"(V.x), "v"(V.y), "v"(V.z), "v"(V.w))
#define PIN8(E) do { PINV(E##0); PINV(E##1); PINV(E##2); PINV(E##3);         \
                     PINV(E##4); PINV(E##5); PINV(E##6); PINV(E##7); } while (0)

      // EV holds the PRECOMPUTED weights for this step (4 odd-state weights)
#define STEP1(EV) do {                                                       \
    const float pm1 = shr1z(b3);                                             \
    const float t0_ = a0 + pm1;                                              \
    const float t1_ = a1 + b0;                                               \
    const float t2_ = a2 + b1;                                               \
    const float t3_ = a3 + b2;                                               \
    s512 = s512 + b3;                                                        \
    b0 = (b0 + t0_) * EV.x;                                                  \
    b1 = (b1 + t1_) * EV.y;                                                  \
    b2 = (b2 + t2_) * EV.z;                                                  \
    b3 = (b3 + t3_) * EV.w;                                                  \
    a0 = t0_; a1 = t1_; a2 = t2_; a3 = t3_;                                  \
  } while (0)

#define STEP1G(EV, J) do { if ((J) < rem_) { STEP1(EV); } } while (0)

#define RUN8(E)  do { STEP1(E##0); STEP1(E##1); STEP1(E##2); STEP1(E##3);    \
                      STEP1(E##4); STEP1(E##5); STEP1(E##6); STEP1(E##7); } while (0)
#define RUN8G(E, RM) do { const int rem_ = (RM);                             \
                      STEP1G(E##0,0); STEP1G(E##1,1); STEP1G(E##2,2);        \
                      STEP1G(E##3,3); STEP1G(E##4,4); STEP1G(E##5,5);        \
                      STEP1G(E##6,6); STEP1G(E##7,7); } while (0)

#define APPLY() do {                                                         \
    int e_ = (int)((__float_as_uint(m_red) >> 23) & 0xFF) - 127;             \
    if (!(m_red > 0.f)) e_ = -24;                                            \
    const int k_ = e_ + 24;              /* normalize max to 2^-24 */        \
    if (k_ > 126) {                                                          \
      const int kh_ = k_ >> 1;                                               \
      const float s1_ = exp2i(-kh_), s2_ = exp2i(-(k_ - kh_));               \
      a0 *= s1_; a1 *= s1_; a2 *= s1_; a3 *= s1_;                            \
      b0 *= s1_; b1 *= s1_; b2 *= s1_; b3 *= s1_; s512 *= s1_;               \
      a0 *= s2_; a1 *= s2_; a2 *= s2_; a3 *= s2_;                            \
      b0 *= s2_; b1 *= s2_; b2 *= s2_; b3 *= s2_; s512 *= s2_;               \
    } else {                                                                 \
      const float s_ = exp2i(-k_);                                           \
      a0 *= s_; a1 *= s_; a2 *= s_; a3 *= s_;                                \
      b0 *= s_; b1 *= s_; b2 *= s_; b3 *= s_; s512 *= s_;                    \
    }                                                                        \
    Cw += k_;                                                                \
  } while (0)

#define MEASURE() do {                                                       \
    float ml_ = fmaxf(fmaxf(fmaxf(a0, a1), fmaxf(a2, a3)),                   \
                      fmaxf(fmaxf(b0, b1), fmaxf(b2, b3)));                  \
    ml_ = fmaxf(ml_, s512);                                                  \
    m_red = dmax64(ml_);                                                     \
  } while (0)

#define RUNGRP(E, G) do {                                                    \
    PIN8(E);                                                                 \
    if (8 * (G) + 8 <= total) { RUN8(E); }                                   \
    else { RUN8G(E, total - 8 * (G)); }                                      \
    APPLY(); MEASURE();                                                      \
  } while (0)

      POLL(3);
      LD8(e, 0);
      if (1 < ng) LD8(f, 1);
      if (2 < ng) LD8(g, 2);
      int cg = 0;
      // -------- main loop: fully-live groups, prefetch always valid --------
      while (cg + 6 <= ng && 8 * (cg + 3) <= total) {
        POLL(cg + 6);
        PIN8(e); RUN8(e); APPLY(); MEASURE(); LD8(e, cg + 3);
        PIN8(f); RUN8(f); APPLY(); MEASURE(); LD8(f, cg + 4);
        PIN8(g); RUN8(g); APPLY(); MEASURE(); LD8(g, cg + 5);
        __asm__ __volatile__("" ::: "memory");
        if (lane == 0) *(volatile int*)&consG = cg + 6;  // after LD8s (in-order DS)
        cg += 3;
      }
      // -------- guarded tail --------
      for (; cg < ng; cg += 3) {
        POLL(min(cg + 6, ng));
        RUNGRP(e, cg);
        if (cg + 3 < ng) LD8(e, cg + 3);
        if (cg + 1 < ng) {
          RUNGRP(f, cg + 1);
          if (cg + 4 < ng) LD8(f, cg + 4);
        }
        if (cg + 2 < ng) {
          RUNGRP(g, cg + 2);
          if (cg + 5 < ng) LD8(g, cg + 5);
        }
        __asm__ __volatile__("" ::: "memory");
        if (lane == 0) *(volatile int*)&consG = cg + 6;
      }
#undef POLL
#undef LD8
#undef PINV
#undef PIN8
#undef STEP1
#undef STEP1G
#undef RUN8
#undef RUN8G
#undef APPLY
#undef MEASURE
#undef RUNGRP

      // readout: a_last = state 2*kl, a_prev = state 2*kl-1
      float* ev = (float*)ring;
      float* od = (float*)(ring + 4096);
      *(float4*)(ev + (lane << 2)) = make_float4(a0, a1, a2, a3);
      *(float4*)(od + (lane << 2)) = make_float4(b0, b1, b2, b3);
      if (lane == 63) *(float*)(ring + 8192) = s512;
      __asm__ __volatile__("" ::: "memory");
      if (lane == 0) {
        const float aL = (kl < 256) ? ev[kl] : *(float*)(ring + 8192);
        const float aP = od[kl - 1];
        const float dC = (float)Cw - (float)total * LOG2E;  // e-fold removal
        alast[b] = (log2f(aL) + dC) * LN2f;
        aprev[b] = (log2f(aP) + dC) * LN2f;
      }
    } else {
      // ========== producers: waves 1..3 — exp2 + ds_write ONLY ==========
      const int pw = w - 1;                    // handles groups g % 3 == pw
      const int c0 = lane << 2;
      const float bs0 = (c0 + 0 < kl) ? LOG2E : -20000.f;
      const float bs1 = (c0 + 1 < kl) ? LOG2E : -20000.f;
      const float bs2 = (c0 + 2 < kl) ? LOG2E : -20000.f;
      const float bs3 = (c0 + 3 < kl) ? LOG2E : -20000.f;
      volatile int* vc = &consG;

      float4 A0, A1, A2, A3, A4, A5, A6, A7;
      float4 B0, B1, B2, B3, B4, B5, B6, B7;
      float4 C0, C1, C2, C3, C4, C5, C6, C7;

#define LOADG(P, GG) do {                                                    \
    const int rb_ = 8 * (GG) + 1;                                            \
    P##0 = *(const float4*)(xbc + (size_t)min(rb_ + 0, TB - 1) * 1024 + lane16); \
    P##1 = *(const float4*)(xbc + (size_t)min(rb_ + 1, TB - 1) * 1024 + lane16); \
    P##2 = *(const float4*)(xbc + (size_t)min(rb_ + 2, TB - 1) * 1024 + lane16); \
    P##3 = *(const float4*)(xbc + (size_t)min(rb_ + 3, TB - 1) * 1024 + lane16); \
    P##4 = *(const float4*)(xbc + (size_t)min(rb_ + 4, TB - 1) * 1024 + lane16); \
    P##5 = *(const float4*)(xbc + (size_t)min(rb_ + 5, TB - 1) * 1024 + lane16); \
    P##6 = *(const float4*)(xbc + (size_t)min(rb_ + 6, TB - 1) * 1024 + lane16); \
    P##7 = *(const float4*)(xbc + (size_t)min(rb_ + 7, TB - 1) * 1024 + lane16); \
  } while (0)

#define PR1(V, J) do {                                                       \
    float4 wv_;                                                              \
    wv_.x = __builtin_amdgcn_exp2f(fmaf(V.x, LOG2E, bs0));                   \
    wv_.y = __builtin_amdgcn_exp2f(fmaf(V.y, LOG2E, bs1));                   \
    wv_.z = __builtin_amdgcn_exp2f(fmaf(V.z, LOG2E, bs2));                   \
    wv_.w = __builtin_amdgcn_exp2f(fmaf(V.w, LOG2E, bs3));                   \
    *(float4*)(dstb_ + ((J) << 10)) = wv_;                                   \
  } while (0)

#define PROC(P, GG) do {                                                     \
    if ((GG) >= 8) {                        /* ring slot reuse */            \
      int c_ = *vc;                                                          \
      while (c_ < (GG) - 7) { __builtin_amdgcn_s_sleep(2); c_ = *vc; }       \
      __asm__ __volatile__("" ::: "memory");                                 \
    }                                                                        \
    char* dstb_ = ring + (((GG) & 7) << 13) + lane16;                        \
    PR1(P##0, 0); PR1(P##1, 1); PR1(P##2, 2); PR1(P##3, 3);                  \
    PR1(P##4, 4); PR1(P##5, 5); PR1(P##6, 6); PR1(P##7, 7);                  \
    __asm__ __volatile__("s_waitcnt lgkmcnt(0)" ::: "memory");               \
    if (lane == 0) *(volatile int*)&prodG[pw] = (GG) + 3;                    \
  } while (0)

      LOADG(A, pw); LOADG(B, pw + 3);
      int g = pw;
      for (;;) {
        LOADG(C, g + 6);
        PROC(A, g);
        g += 3; if (g >= ng) break;
        LOADG(A, g + 6);
        PROC(B, g);
        g += 3; if (g >= ng) break;
        LOADG(B, g + 6);
        PROC(C, g);
        g += 3; if (g >= ng) break;
      }
#undef LOADG
#undef PR1
#undef PROC
      __asm__ __volatile__("" ::: "memory");
      if (lane == 0) *(volatile int*)&prodG[pw] = 0x7fffffff;
    }

  } else {
    // -------- lse row partials: 16 rows/wave, DPP sum, no max pass --------
    const int gwid = (blockIdx.x - BB) * 4 + w;            // [0, 8000)
    const int b    = gwid / WPB;
    const int widx = gwid - b * WPB;
    const int kl   = key_lens[b];
    const int qlen = query_lens[b];
    const float* xb = x + (size_t)b * (TB * KB);
    const int c0 = lane * 4;
    const float bA = (c0 + 0 < kl) ? 0.f : -20000.f;
    const float bBv= (c0 + 1 < kl) ? 0.f : -20000.f;
    const float bC = (c0 + 2 < kl) ? 0.f : -20000.f;
    const float bD = (c0 + 3 < kl) ? 0.f : -20000.f;
    const int tbase = widx * RPW;
#define LSELOAD(k) const float4 v##k =                                       \
    *(const float4*)(xb + (size_t)(tbase + (k)) * KB + c0);
    LSELOAD(0)  LSELOAD(1)  LSELOAD(2)  LSELOAD(3)
    LSELOAD(4)  LSELOAD(5)  LSELOAD(6)  LSELOAD(7)
    LSELOAD(8)  LSELOAD(9)  LSELOAD(10) LSELOAD(11)
    LSELOAD(12) LSELOAD(13) LSELOAD(14) LSELOAD(15)
#undef LSELOAD
    float acc = 0.f;
#define LSEROW(k) do {                                                       \
    float s = __builtin_amdgcn_exp2f(fmaf(v##k.x, LOG2E, bA))                \
            + __builtin_amdgcn_exp2f(fmaf(v##k.y, LOG2E, bBv))               \
            + __builtin_amdgcn_exp2f(fmaf(v##k.z, LOG2E, bC))                \
            + __builtin_amdgcn_exp2f(fmaf(v##k.w, LOG2E, bD));               \
    s = dsum64(s);                                                           \
    s += WBF;                                                                \
    acc += ((tbase + (k)) < qlen) ? __builtin_amdgcn_logf(s) : 0.f;          \
  } while (0)
    LSEROW(0);  LSEROW(1);  LSEROW(2);  LSEROW(3);
    LSEROW(4);  LSEROW(5);  LSEROW(6);  LSEROW(7);
    LSEROW(8);  LSEROW(9);  LSEROW(10); LSEROW(11);
    LSEROW(12); LSEROW(13); LSEROW(14); LSEROW(15);
#undef LSEROW
    if (lane == 63) partial[gwid] = acc * LN2f;
  }
}

// ---------------------------------------------------------------------------
// finish: per-batch SumLse + loss + mean, one block (r5-proven).
// ---------------------------------------------------------------------------
__global__ __launch_bounds__(256)
void fsl_finish(const float* __restrict__ partial, const int* __restrict__ key_lens,
                const float* __restrict__ alast, const float* __restrict__ aprev,
                float* __restrict__ out) {
  const int tid = threadIdx.x;
  const int b = tid >> 2, q = tid & 3;
  float s = 0.f;
  for (int j = q; j < WPB; j += 4) s += partial[b * WPB + j];
  s += __shfl_xor(s, 1, 64);
  s += __shfl_xor(s, 2, 64);
  float lossb = 0.f;
  if (q == 0) {
    const float SumLse = s;
    const float al = alast[b], ap = aprev[b];
    const float mx = fmaxf(al, ap);
    const float lae = (mx == -INFINITY) ? -INFINITY
                                        : mx + log1pf(expf(-fabsf(al - ap)));
    const float nll = SumLse - lae;
    const int kl = key_lens[b];
    float lv = nll / (float)max(kl, 1);
    if (nll > 5e29f) lv = 0.f;
    lossb = lv;
  }
  float v = wsum64(lossb);
  __shared__ float sm[4];
  if ((tid & 63) == 0) sm[tid >> 6] = v;
  __syncthreads();
  if (tid == 0) out[0] = ((sm[0] + sm[1]) + (sm[2] + sm[3])) * (1.0f / 64.0f);
}

extern "C" void kernel_launch(void* const* d_in, const int* in_sizes, int n_in,
                              void* d_out, int out_size, void* d_ws, size_t ws_size,
                              hipStream_t stream) {
  const float* x     = (const float*)d_in[0];
  const int*   klens = (const int*)d_in[1];
  const int*   qlens = (const int*)d_in[2];
  float* out = (float*)d_out;

  float* partial = (float*)d_ws;            // 64*125 = 8000 floats
  float* alast   = partial + BB * WPB;      // 64
  float* aprev   = alast + BB;              // 64

  fsl_main  <<<BB + NLSEB, 256, 0, stream>>>(x, klens, qlens, partial, alast, aprev);
  fsl_finish<<<1, 256, 0, stream>>>(partial, klens, alast, aprev, out);
}